// Round 1
// baseline (639.926 us; speedup 1.0000x reference)
//
#include <hip/hip_runtime.h>

// Problem constants (fixed by setup_inputs).
#define N_NODES 30000
#define N_EDGES 480000
#define NB      32
#define HEADS   8
#define HID     64
#define F1      512      // HEADS*HID
#define OUT_C   129

// Active-set capacities (expected: n1~550, n0~8300, m1~8700, m2~512).
#define CAP0   12288
#define CAP1   4096
#define CAPE1  16384
#define CAPE2  2048

__device__ __forceinline__ unsigned fenc(float f) {
    unsigned u = __float_as_uint(f);
    return (u & 0x80000000u) ? ~u : (u | 0x80000000u);
}
__device__ __forceinline__ float fdec(unsigned e) {
    return (e & 0x80000000u) ? __uint_as_float(e ^ 0x80000000u) : __uint_as_float(~e);
}
__device__ __forceinline__ float lrelu(float a) { return a > 0.f ? a : 0.2f * a; }

// ---- shared setup ----
__global__ void k_last(const int* __restrict__ batch, int* __restrict__ last) {
    int i = blockIdx.x * 256 + threadIdx.x;
    if (i >= N_NODES) return;
    int b = batch[i];
    if (i == N_NODES - 1 || batch[i + 1] != b) last[b] = i;
}

// k1[h] = sum_c We1[h*64+c]*ae1[h,c];  k2 = sum_c We2[c]*ae2[c]   (edge_dim == 1)
__global__ void k_prek(const float* We1h, const float* ae1h,
                       const float* We1p, const float* ae1p,
                       const float* We2h, const float* ae2h,
                       const float* We2p, const float* ae2p,
                       float* k12) {
    int t = threadIdx.x;
    if (t < 8) {
        float s = 0.f;
        for (int c = 0; c < 64; c++) s += We1h[t * 64 + c] * ae1h[t * 64 + c];
        k12[t] = s;
    } else if (t < 16) {
        int h = t - 8;
        float s = 0.f;
        for (int c = 0; c < 64; c++) s += We1p[h * 64 + c] * ae1p[h * 64 + c];
        k12[8 + h] = s;
    } else if (t == 16) {
        float s = 0.f;
        for (int c = 0; c < OUT_C; c++) s += We2h[c] * ae2h[c];
        k12[16] = s;
    } else if (t == 17) {
        float s = 0.f;
        for (int c = 0; c < OUT_C; c++) s += We2p[c] * ae2p[c];
        k12[17] = s;
    }
}

// ---- per-branch pipeline ----
__global__ void k_init(int* inv0, int* inv1, int* inv2, float* deg, float* easum,
                       float* hacc1, float* denom1, unsigned* amax1,
                       float* acc2, float* denom2, unsigned* amax2, int* cnt) {
    int i = blockIdx.x * 256 + threadIdx.x;
    if (i < N_NODES) { inv0[i] = -1; inv1[i] = -1; inv2[i] = -1; deg[i] = 0.f; easum[i] = 0.f; }
    if (i < CAP1 * F1) hacc1[i] = 0.f;
    if (i < CAP1 * HEADS) { denom1[i] = 0.f; amax1[i] = 0u; }
    if (i < NB * OUT_C) acc2[i] = 0.f;
    if (i < NB) { denom2[i] = 0.f; amax2[i] = 0u; }
    if (i < 8) cnt[i] = 0;
}

__global__ void k_deg(const int* __restrict__ dst, const float* __restrict__ ea,
                      float* deg, float* easum) {
    int e = blockIdx.x * 256 + threadIdx.x;
    if (e >= N_EDGES) return;
    int t = dst[e];
    atomicAdd(deg + t, 1.f);
    atomicAdd(easum + t, ea[e]);
}

__global__ void k_mark2(const int* last, int* inv2, int* inv1) {
    int b = threadIdx.x;
    if (b >= NB) return;
    int v = last[b];
    inv2[v] = b;
    inv1[v] = -2;   // last nodes need their own h1 (self-loop + a_d)
}

__global__ void k_scan2(const int* __restrict__ src, const int* __restrict__ dst,
                        const int* __restrict__ inv2, int* inv1, int* edges2, int* cnt) {
    int e = blockIdx.x * 256 + threadIdx.x;
    if (e >= N_EDGES) return;
    if (inv2[dst[e]] >= 0) {
        int p = atomicAdd(cnt + 3, 1);
        if (p < CAPE2) edges2[p] = e;
        inv1[src[e]] = -2;           // benign same-value race
    }
}

__global__ void k_compact1(int* inv1, int* inv0, int* nodes1, int* cnt) {
    int v = blockIdx.x * 256 + threadIdx.x;
    if (v >= N_NODES) return;
    if (inv1[v] == -2) {
        int j = atomicAdd(cnt + 0, 1);
        if (j < CAP1) { inv1[v] = j; nodes1[j] = v; }
        inv0[v] = -2;                // A1 subset of A0 (self-loop source)
    }
}

__global__ void k_scan1(const int* __restrict__ src, const int* __restrict__ dst,
                        const int* __restrict__ inv1, int* inv0, int* edges1, int* cnt) {
    int e = blockIdx.x * 256 + threadIdx.x;
    if (e >= N_EDGES) return;
    if (inv1[dst[e]] >= 0) {
        int p = atomicAdd(cnt + 2, 1);
        if (p < CAPE1) edges1[p] = e;
        inv0[src[e]] = -2;
    }
}

__global__ void k_compact0(int* inv0, int* nodes0, int* cnt) {
    int v = blockIdx.x * 256 + threadIdx.x;
    if (v >= N_NODES) return;
    if (inv0[v] == -2) {
        int i = atomicAdd(cnt + 1, 1);
        if (i < CAP0) { inv0[v] = i; nodes0[i] = v; }
    }
}

// xw1c[i,:] = x[nodes0[i],:] @ W1   (M=n0, K in {129,15}, N=512), 64x64 tile, 4x4/thread
__global__ __launch_bounds__(256) void k_gemm1(const float* __restrict__ x, int K,
        const float* __restrict__ W, const int* __restrict__ nodes0, const int* cnt,
        float* __restrict__ out) {
    __shared__ float As[16][64];
    __shared__ float Bs[16][64];
    int n0 = cnt[1]; if (n0 > CAP0) n0 = CAP0;
    int rb = blockIdx.x >> 3, cb = blockIdx.x & 7;
    int row0 = rb * 64, col0 = cb * 64;
    if (row0 >= n0) return;
    int tid = threadIdx.x;
    int ty = tid >> 4, tx = tid & 15;
    float acc[4][4];
#pragma unroll
    for (int i = 0; i < 4; i++)
#pragma unroll
        for (int j = 0; j < 4; j++) acc[i][j] = 0.f;

    int nk = (K + 15) / 16;
    for (int kt = 0; kt < nk; kt++) {
        int k0 = kt * 16;
#pragma unroll
        for (int r = 0; r < 4; r++) {
            int mi = (tid >> 4) + r * 16;
            int kk = tid & 15;
            int row = row0 + mi;
            float v = 0.f;
            if (row < n0 && (k0 + kk) < K) v = x[nodes0[row] * K + k0 + kk];
            As[kk][mi] = v;
        }
#pragma unroll
        for (int r = 0; r < 4; r++) {
            int kk = (tid >> 6) + r * 4;
            int ni = tid & 63;
            float v = 0.f;
            if ((k0 + kk) < K) v = W[(k0 + kk) * F1 + col0 + ni];
            Bs[kk][ni] = v;
        }
        __syncthreads();
#pragma unroll
        for (int kk = 0; kk < 16; kk++) {
            float a[4], b[4];
#pragma unroll
            for (int i = 0; i < 4; i++) a[i] = As[kk][ty * 4 + i];
#pragma unroll
            for (int i = 0; i < 4; i++) b[i] = Bs[kk][tx * 4 + i];
#pragma unroll
            for (int i = 0; i < 4; i++)
#pragma unroll
                for (int j = 0; j < 4; j++) acc[i][j] += a[i] * b[j];
        }
        __syncthreads();
    }
#pragma unroll
    for (int i = 0; i < 4; i++) {
        int row = row0 + ty * 4 + i;
        if (row >= n0) continue;
#pragma unroll
        for (int j = 0; j < 4; j++) out[row * F1 + col0 + tx * 4 + j] = acc[i][j];
    }
}

__global__ void k_as0(const float* __restrict__ xw, const float* __restrict__ a_src,
                      const int* cnt, float* as0) {
    int idx = blockIdx.x * 256 + threadIdx.x;
    int i = idx >> 3, h = idx & 7;
    int n0 = cnt[1]; if (n0 > CAP0) n0 = CAP0;
    if (i >= n0) return;
    const float* xp = xw + i * F1 + h * 64;
    const float* ap = a_src + h * 64;
    float s = 0.f;
    for (int c = 0; c < 64; c++) s += xp[c] * ap[c];
    as0[idx] = s;
}

__global__ void k_ad1(const float* __restrict__ xw, const float* __restrict__ a_dst,
                      const int* nodes1, const int* inv0, const int* cnt, float* ad1v) {
    int idx = blockIdx.x * 256 + threadIdx.x;
    int j = idx >> 3, h = idx & 7;
    int n1 = cnt[0]; if (n1 > CAP1) n1 = CAP1;
    if (j >= n1) return;
    int i = inv0[nodes1[j]];
    const float* xp = xw + i * F1 + h * 64;
    const float* ap = a_dst + h * 64;
    float s = 0.f;
    for (int c = 0; c < 64; c++) s += xp[c] * ap[c];
    ad1v[idx] = s;
}

// one wave per (edge or self-loop); pass0 = segment max (exact), pass1 = exp-sum + message accum
__global__ void k_edge1(int pass, const int* __restrict__ src, const int* __restrict__ dst,
        const float* __restrict__ ea, const float* __restrict__ deg, const float* __restrict__ easum,
        const int* __restrict__ edges1, const int* __restrict__ nodes1,
        const int* __restrict__ inv0, const int* __restrict__ inv1, const int* cnt,
        const float* __restrict__ as0, const float* __restrict__ ad1v, const float* __restrict__ k1,
        const float* __restrict__ xw, unsigned* amax1, float* denom1, float* hacc1) {
    int w = blockIdx.x * 4 + (threadIdx.x >> 6);
    int lane = threadIdx.x & 63;
    int m1 = cnt[2]; if (m1 > CAPE1) m1 = CAPE1;
    int n1 = cnt[0]; if (n1 > CAP1) n1 = CAP1;
    int i, j; float eav;
    if (w < CAPE1) {
        if (w >= m1) return;
        int e = edges1[w];
        i = inv0[src[e]];
        j = inv1[dst[e]];
        eav = ea[e];
    } else {
        int jj = w - CAPE1;
        if (jj >= n1) return;
        int v = nodes1[jj];
        i = inv0[v];
        j = jj;
        eav = easum[v] / fmaxf(deg[v], 1.f);
    }
    float alpha[8];
#pragma unroll
    for (int h = 0; h < 8; h++)
        alpha[h] = lrelu(as0[i * 8 + h] + ad1v[j * 8 + h] + eav * k1[h]);
    if (pass == 0) {
        if (lane < 8) atomicMax(amax1 + j * 8 + lane, fenc(alpha[lane]));
    } else {
        float ex[8];
#pragma unroll
        for (int h = 0; h < 8; h++) ex[h] = __expf(alpha[h] - fdec(amax1[j * 8 + h]));
        if (lane < 8) atomicAdd(denom1 + j * 8 + lane, ex[lane]);
#pragma unroll
        for (int h = 0; h < 8; h++)
            atomicAdd(hacc1 + j * F1 + h * 64 + lane, ex[h] * xw[i * F1 + h * 64 + lane]);
    }
}

// h1 = elu(acc/denom + b1), in place
__global__ void k_h1(const float* __restrict__ denom1, const float* __restrict__ b1,
                     const int* cnt, float* hacc1) {
    int idx = blockIdx.x * 256 + threadIdx.x;
    int j = idx / F1, q = idx % F1;
    int n1 = cnt[0]; if (n1 > CAP1) n1 = CAP1;
    if (j >= n1) return;
    float v = hacc1[idx] / denom1[j * 8 + (q >> 6)] + b1[q];
    hacc1[idx] = v > 0.f ? v : (__expf(v) - 1.f);
}

// xw2[j,:] = h1[j,:] @ W2   (K=512, N=129); 2 rows per 256-thread block
__global__ __launch_bounds__(256) void k_gemm2(const float* __restrict__ h1,
        const float* __restrict__ W2, const int* cnt, float* __restrict__ xw2) {
    __shared__ float hs[2][512];
    int n1 = cnt[0]; if (n1 > CAP1) n1 = CAP1;
    int j0 = blockIdx.x * 2;
    if (j0 >= n1) return;
    int tid = threadIdx.x;
    for (int r = 0; r < 2; r++) {
        int j = j0 + r;
        for (int k = tid; k < 512; k += 256) hs[r][k] = (j < n1) ? h1[j * F1 + k] : 0.f;
    }
    __syncthreads();
    int jj = tid >> 7, cl = tid & 127;
    float acc0 = 0.f, acc1 = 0.f;
    for (int k = 0; k < 512; k++) {
        float hv = hs[jj][k];
        acc0 += hv * W2[k * OUT_C + cl];
        if (cl == 0) acc1 += hv * W2[k * OUT_C + 128];
    }
    int j = j0 + jj;
    if (j < n1) {
        xw2[j * OUT_C + cl] = acc0;
        if (cl == 0) xw2[j * OUT_C + 128] = acc1;
    }
}

__global__ void k_attn2(const float* __restrict__ xw2, const float* __restrict__ as2w,
                        const float* __restrict__ ad2w, const int* last, const int* inv1,
                        const int* cnt, float* as2v, float* ad2v) {
    int idx = blockIdx.x * 256 + threadIdx.x;
    int n1 = cnt[0]; if (n1 > CAP1) n1 = CAP1;
    if (idx < CAP1) {
        if (idx < n1) {
            float s = 0.f;
            for (int c = 0; c < OUT_C; c++) s += xw2[idx * OUT_C + c] * as2w[c];
            as2v[idx] = s;
        }
    } else {
        int b = idx - CAP1;
        if (b < NB) {
            int j = inv1[last[b]];
            float s = 0.f;
            for (int c = 0; c < OUT_C; c++) s += xw2[j * OUT_C + c] * ad2w[c];
            ad2v[b] = s;
        }
    }
}

__global__ void k_edge2(int pass, const int* __restrict__ src, const int* __restrict__ dst,
        const float* __restrict__ ea, const float* __restrict__ deg, const float* __restrict__ easum,
        const int* __restrict__ edges2, const int* last,
        const int* __restrict__ inv1, const int* __restrict__ inv2, const int* cnt,
        const float* __restrict__ as2v, const float* __restrict__ ad2v, const float* k2p,
        const float* __restrict__ xw2, unsigned* amax2, float* denom2, float* acc2) {
    int w = blockIdx.x * 4 + (threadIdx.x >> 6);
    int lane = threadIdx.x & 63;
    int m2 = cnt[3]; if (m2 > CAPE2) m2 = CAPE2;
    int j, b; float eav;
    if (w < CAPE2) {
        if (w >= m2) return;
        int e = edges2[w];
        j = inv1[src[e]];
        b = inv2[dst[e]];
        eav = ea[e];
    } else {
        b = w - CAPE2;
        if (b >= NB) return;
        int v = last[b];
        j = inv1[v];
        eav = easum[v] / fmaxf(deg[v], 1.f);
    }
    float a = lrelu(as2v[j] + ad2v[b] + eav * (*k2p));
    if (pass == 0) {
        if (lane == 0) atomicMax(amax2 + b, fenc(a));
    } else {
        float ex = __expf(a - fdec(amax2[b]));
        if (lane == 0) atomicAdd(denom2 + b, ex);
        for (int c = lane; c < OUT_C; c += 64)
            atomicAdd(acc2 + b * OUT_C + c, ex * xw2[j * OUT_C + c]);
    }
}

__global__ void k_out(const float* __restrict__ acc2, const float* __restrict__ denom2,
                      const float* __restrict__ b2, float* hout) {
    int idx = blockIdx.x * 256 + threadIdx.x;
    if (idx >= NB * OUT_C) return;
    int b = idx / OUT_C, c = idx % OUT_C;
    hout[idx] = acc2[idx] / denom2[b] + b2[c];
}

__global__ void k_fc(const float* __restrict__ houth, const float* __restrict__ houtp,
                     const float* __restrict__ Wfc, const float* __restrict__ bfc,
                     float* __restrict__ out) {
    __shared__ float cat[2 * OUT_C];
    int b = blockIdx.x, tid = threadIdx.x;
    for (int t = tid; t < 2 * OUT_C; t += 256)
        cat[t] = (t < OUT_C) ? houth[b * OUT_C + t] : houtp[b * OUT_C + t - OUT_C];
    __syncthreads();
    if (tid < OUT_C) {
        float s = bfc[tid];
        for (int k = 0; k < 2 * OUT_C; k++) s += cat[k] * Wfc[k * OUT_C + tid];
        out[b * OUT_C + tid] = s;
    }
}

extern "C" void kernel_launch(void* const* d_in, const int* in_sizes, int n_in,
                              void* d_out, int out_size, void* d_ws, size_t ws_size,
                              hipStream_t stream) {
    const float* x_h  = (const float*)d_in[0];
    const float* x_p  = (const float*)d_in[1];
    const float* ea_h = (const float*)d_in[2];
    const float* ea_p = (const float*)d_in[3];
    const float* W1h  = (const float*)d_in[4];
    const float* as1h = (const float*)d_in[5];
    const float* ad1h = (const float*)d_in[6];
    const float* We1h = (const float*)d_in[7];
    const float* ae1h = (const float*)d_in[8];
    const float* b1h  = (const float*)d_in[9];
    const float* W2h  = (const float*)d_in[10];
    const float* as2h = (const float*)d_in[11];
    const float* ad2h = (const float*)d_in[12];
    const float* We2h = (const float*)d_in[13];
    const float* ae2h = (const float*)d_in[14];
    const float* b2h  = (const float*)d_in[15];
    const float* W1p  = (const float*)d_in[16];
    const float* as1p = (const float*)d_in[17];
    const float* ad1p = (const float*)d_in[18];
    const float* We1p = (const float*)d_in[19];
    const float* ae1p = (const float*)d_in[20];
    const float* b1p  = (const float*)d_in[21];
    const float* W2p  = (const float*)d_in[22];
    const float* as2p = (const float*)d_in[23];
    const float* ad2p = (const float*)d_in[24];
    const float* We2p = (const float*)d_in[25];
    const float* ae2p = (const float*)d_in[26];
    const float* b2p  = (const float*)d_in[27];
    const float* Wfc  = (const float*)d_in[28];
    const float* bfc  = (const float*)d_in[29];
    const int*   ei_h = (const int*)d_in[30];
    const int*   ei_p = (const int*)d_in[31];
    const int*   batch = (const int*)d_in[32];

    // workspace carve (256B aligned chunks); total ~37.5 MB
    char* wsb = (char*)d_ws;
    size_t off = 0;
    auto alloc = [&](size_t elems) -> char* {
        char* p = wsb + off;
        off += ((elems * 4 + 255) / 256) * 256;
        return p;
    };
    int*      last   = (int*)alloc(NB);
    float*    k12    = (float*)alloc(18);
    int*      cnt    = (int*)alloc(8);
    int*      inv0   = (int*)alloc(N_NODES);
    int*      inv1   = (int*)alloc(N_NODES);
    int*      inv2   = (int*)alloc(N_NODES);
    float*    deg    = (float*)alloc(N_NODES);
    float*    easum  = (float*)alloc(N_NODES);
    int*      nodes0 = (int*)alloc(CAP0);
    int*      nodes1 = (int*)alloc(CAP1);
    int*      edges1 = (int*)alloc(CAPE1);
    int*      edges2 = (int*)alloc(CAPE2);
    float*    xw1c   = (float*)alloc((size_t)CAP0 * F1);
    float*    as0    = (float*)alloc((size_t)CAP0 * HEADS);
    float*    ad1v   = (float*)alloc((size_t)CAP1 * HEADS);
    unsigned* amax1  = (unsigned*)alloc((size_t)CAP1 * HEADS);
    float*    denom1 = (float*)alloc((size_t)CAP1 * HEADS);
    float*    hacc1  = (float*)alloc((size_t)CAP1 * F1);
    float*    xw2    = (float*)alloc((size_t)CAP1 * OUT_C);
    float*    as2v   = (float*)alloc(CAP1);
    float*    ad2v   = (float*)alloc(NB);
    unsigned* amax2  = (unsigned*)alloc(NB);
    float*    denom2 = (float*)alloc(NB);
    float*    acc2   = (float*)alloc(NB * OUT_C);
    float*    houth  = (float*)alloc(NB * OUT_C);
    float*    houtp  = (float*)alloc(NB * OUT_C);
    if (off > ws_size) return;  // workspace too small — fail loudly via poison output

    const int EBLK = (N_EDGES + 255) / 256;
    const int NBLK = (N_NODES + 255) / 256;

    k_last<<<NBLK, 256, 0, stream>>>(batch, last);
    k_prek<<<1, 64, 0, stream>>>(We1h, ae1h, We1p, ae1p, We2h, ae2h, We2p, ae2p, k12);

    auto run_branch = [&](const float* x, int K, const int* ei, const float* ea,
                          const float* W1, const float* as1, const float* ad1w, const float* b1,
                          const float* W2, const float* as2w, const float* ad2w, const float* b2,
                          const float* k1, const float* k2p, float* hout_br) {
        const int* srcp = ei;
        const int* dstp = ei + N_EDGES;
        k_init<<<(CAP1 * F1) / 256, 256, 0, stream>>>(inv0, inv1, inv2, deg, easum,
                                                      hacc1, denom1, amax1, acc2, denom2, amax2, cnt);
        k_deg<<<EBLK, 256, 0, stream>>>(dstp, ea, deg, easum);
        k_mark2<<<1, 64, 0, stream>>>(last, inv2, inv1);
        k_scan2<<<EBLK, 256, 0, stream>>>(srcp, dstp, inv2, inv1, edges2, cnt);
        k_compact1<<<NBLK, 256, 0, stream>>>(inv1, inv0, nodes1, cnt);
        k_scan1<<<EBLK, 256, 0, stream>>>(srcp, dstp, inv1, inv0, edges1, cnt);
        k_compact0<<<NBLK, 256, 0, stream>>>(inv0, nodes0, cnt);
        k_gemm1<<<(CAP0 / 64) * 8, 256, 0, stream>>>(x, K, W1, nodes0, cnt, xw1c);
        k_as0<<<(CAP0 * HEADS) / 256, 256, 0, stream>>>(xw1c, as1, cnt, as0);
        k_ad1<<<(CAP1 * HEADS) / 256, 256, 0, stream>>>(xw1c, ad1w, nodes1, inv0, cnt, ad1v);
        k_edge1<<<(CAPE1 + CAP1) / 4, 256, 0, stream>>>(0, srcp, dstp, ea, deg, easum, edges1,
                nodes1, inv0, inv1, cnt, as0, ad1v, k1, xw1c, amax1, denom1, hacc1);
        k_edge1<<<(CAPE1 + CAP1) / 4, 256, 0, stream>>>(1, srcp, dstp, ea, deg, easum, edges1,
                nodes1, inv0, inv1, cnt, as0, ad1v, k1, xw1c, amax1, denom1, hacc1);
        k_h1<<<(CAP1 * F1) / 256, 256, 0, stream>>>(denom1, b1, cnt, hacc1);
        k_gemm2<<<CAP1 / 2, 256, 0, stream>>>(hacc1, W2, cnt, xw2);
        k_attn2<<<(CAP1 + NB + 255) / 256, 256, 0, stream>>>(xw2, as2w, ad2w, last, inv1, cnt, as2v, ad2v);
        k_edge2<<<(CAPE2 + NB) / 4, 256, 0, stream>>>(0, srcp, dstp, ea, deg, easum, edges2, last,
                inv1, inv2, cnt, as2v, ad2v, k2p, xw2, amax2, denom2, acc2);
        k_edge2<<<(CAPE2 + NB) / 4, 256, 0, stream>>>(1, srcp, dstp, ea, deg, easum, edges2, last,
                inv1, inv2, cnt, as2v, ad2v, k2p, xw2, amax2, denom2, acc2);
        k_out<<<(NB * OUT_C + 255) / 256, 256, 0, stream>>>(acc2, denom2, b2, hout_br);
    };

    run_branch(x_h, 129, ei_h, ea_h, W1h, as1h, ad1h, b1h, W2h, as2h, ad2h, b2h, k12 + 0, k12 + 16, houth);
    run_branch(x_p, 15,  ei_p, ea_p, W1p, as1p, ad1p, b1p, W2p, as2p, ad2p, b2p, k12 + 8, k12 + 17, houtp);

    k_fc<<<NB, 256, 0, stream>>>(houth, houtp, Wfc, bfc, (float*)d_out);
}